// Round 8
// baseline (298.805 us; speedup 1.0000x reference)
//
#include <hip/hip_runtime.h>
#include <math.h>

#define B      2048
#define NRELS  512
#define FEAT   300
#define LAT    512
#define GRID   448u

typedef __attribute__((ext_vector_type(8))) short short8;
typedef __attribute__((ext_vector_type(4))) float f32x4;

__device__ inline short f2bf(float f) {
    union { float f; unsigned u; } v; v.f = f;
    unsigned u = v.u;
    u += 0x7fffu + ((u >> 16) & 1u);   // RNE
    return (short)(u >> 16);
}

// ================= weight descriptors (transpose tiles) =================
struct WDesc { const float* src; short* dst; int K, N, Kpad, Npad, ilv, ilvoff, tstart, tk; };
struct WPack { WDesc d[9]; };

struct MegaArgs {
    const float* logits; const int* rels; const float* rel_dict;
    const float* fc1_b; const float* mu_b; const float* ls_b;
    const float* fc3_b; const float* fc4_b;
    const float* qi1_b; const float* qi2_b; const float* qz1_b; const float* qz2_b;
    const float* eps1;  const float* eps2;
    float* out; float* zp;
    float* acc;          // [0]=kl [1]=recon [2]=csl, ((unsigned*)acc)[3]=done
    unsigned* bar;       // 16 leaves @ i*64 uints, root @ 16*64, gen @ 17*64
    int* top_idx; int* dis_idx;
    short* Rb; short* Ehb; float* E;
    short* xcat; float* xf;
    short* h1; short* zcat; short* zb; short* h3; short* t1;
    const short* w_qi1t; const short* w_qi2t; const short* w_fc1t; const short* w_mulst;
    const short* w_fc3t; const short* w_fc4t; const short* w_qz1t; const short* w_qz2t;
    WPack wp;
};

// ================= tree grid barrier (leaves on separate cache lines) ===========
__device__ inline void gsync(unsigned* bar)
{
    __syncthreads();
    if (threadIdx.x == 0) {
        __threadfence();
        unsigned* leaf = bar + (blockIdx.x & 15) * 64;
        unsigned* root = bar + 16 * 64;
        unsigned* gen  = bar + 17 * 64;
        unsigned my = __hip_atomic_load(gen, __ATOMIC_ACQUIRE, __HIP_MEMORY_SCOPE_AGENT);
        unsigned a  = __hip_atomic_fetch_add(leaf, 1u, __ATOMIC_ACQ_REL, __HIP_MEMORY_SCOPE_AGENT);
        if (a == (GRID / 16u) - 1u) {
            __hip_atomic_store(leaf, 0u, __ATOMIC_RELAXED, __HIP_MEMORY_SCOPE_AGENT);
            unsigned r = __hip_atomic_fetch_add(root, 1u, __ATOMIC_ACQ_REL, __HIP_MEMORY_SCOPE_AGENT);
            if (r == 15u) {
                __hip_atomic_store(root, 0u, __ATOMIC_RELAXED, __HIP_MEMORY_SCOPE_AGENT);
                __hip_atomic_fetch_add(gen, 1u, __ATOMIC_RELEASE, __HIP_MEMORY_SCOPE_AGENT);
            }
        }
        while (__hip_atomic_load(gen, __ATOMIC_RELAXED, __HIP_MEMORY_SCOPE_AGENT) == my) {
            __builtin_amdgcn_s_sleep(32);   // ~0.85 us poll period: no line hammering
        }
        __threadfence();
    }
    __syncthreads();
}

// ================= 64x64 GEMM core (4 waves, BK=64, reg prefetch) =================
template<int ACT, int MODE>   // MODE: 0 bf16 store, 1 f32 store
__device__ __attribute__((always_inline)) void gemm_core(
    short (&As)[128][72], short (&Bs)[64][72],
    int bx, int by,
    const short* __restrict__ A, const short* __restrict__ Bt,
    const float* __restrict__ bias,
    void* __restrict__ Cv, int Nreal, int Kpad, int ldc)
{
    const int wave = threadIdx.x >> 6;
    const int lane = threadIdx.x & 63;
    const int row0 = by * 64;
    const int col0 = bx * 64;

    const int srow = threadIdx.x >> 3;
    const int sk   = (threadIdx.x & 7) * 8;
    const short* Ap0 = A  + (size_t)(row0 + srow)      * Kpad + sk;
    const short* Ap1 = A  + (size_t)(row0 + srow + 32) * Kpad + sk;
    const short* Bp0 = Bt + (size_t)(col0 + srow)      * Kpad + sk;
    const short* Bp1 = Bt + (size_t)(col0 + srow + 32) * Kpad + sk;

    const int frow = lane & 15;
    const int fk   = (lane >> 4) * 8;

    f32x4 acc0 = {0,0,0,0}, acc1 = {0,0,0,0}, acc2 = {0,0,0,0}, acc3 = {0,0,0,0};

    short8 a0 = *(const short8*)Ap0;
    short8 a1 = *(const short8*)Ap1;
    short8 b0 = *(const short8*)Bp0;
    short8 b1 = *(const short8*)Bp1;

    for (int k0 = 0; k0 < Kpad; k0 += 64) {
        *(short8*)&As[srow][sk]      = a0;
        *(short8*)&As[srow + 32][sk] = a1;
        *(short8*)&Bs[srow][sk]      = b0;
        *(short8*)&Bs[srow + 32][sk] = b1;
        __syncthreads();
        int kn = k0 + 64;
        if (kn < Kpad) {
            a0 = *(const short8*)(Ap0 + kn);
            a1 = *(const short8*)(Ap1 + kn);
            b0 = *(const short8*)(Bp0 + kn);
            b1 = *(const short8*)(Bp1 + kn);
        }
#pragma unroll
        for (int kk = 0; kk < 2; ++kk) {
            short8 af  = *(const short8*)&As[wave * 16 + frow][fk + kk * 32];
            short8 bf0 = *(const short8*)&Bs[ 0 + frow][fk + kk * 32];
            short8 bf1 = *(const short8*)&Bs[16 + frow][fk + kk * 32];
            short8 bf2 = *(const short8*)&Bs[32 + frow][fk + kk * 32];
            short8 bf3 = *(const short8*)&Bs[48 + frow][fk + kk * 32];
            acc0 = __builtin_amdgcn_mfma_f32_16x16x32_bf16(af, bf0, acc0, 0, 0, 0);
            acc1 = __builtin_amdgcn_mfma_f32_16x16x32_bf16(af, bf1, acc1, 0, 0, 0);
            acc2 = __builtin_amdgcn_mfma_f32_16x16x32_bf16(af, bf2, acc2, 0, 0, 0);
            acc3 = __builtin_amdgcn_mfma_f32_16x16x32_bf16(af, bf3, acc3, 0, 0, 0);
        }
        __syncthreads();
    }

    const int orow = row0 + wave * 16 + (lane >> 4) * 4;
    f32x4 accs[4] = {acc0, acc1, acc2, acc3};
#pragma unroll
    for (int n0 = 0; n0 < 4; ++n0) {
        int col = col0 + n0 * 16 + frow;
        float bs = bias[col < Nreal ? col : Nreal - 1];
#pragma unroll
        for (int j = 0; j < 4; ++j) {
            float v = accs[n0][j] + bs;
            if (ACT == 1)      v = v > 0.f ? v : 0.f;
            else if (ACT == 2) v = v > 0.f ? v : 0.2f * v;
            else if (ACT == 3) v = 1.f / (1.f + expf(-v));
            size_t idx = (size_t)(orow + j) * ldc + col;
            if (MODE == 1) ((float*)Cv)[idx] = v;
            else           ((short*)Cv)[idx] = f2bf(v);
        }
    }
}

// ================= 128x64 GEMM tile =================
// MODE: 0 bf16 store, 1 f32 store, 2 fc4 sigmoid+recon fuse, 3 mu/ls sample fuse
template<int ACT, int MODE>
__device__ __attribute__((always_inline)) void gemm_tile(
    short (&As)[128][72], short (&Bs)[64][72],
    int tx, int ty,
    const short* __restrict__ A, const short* __restrict__ Bt,
    const float* __restrict__ bias, const float* __restrict__ bias2,
    void* __restrict__ Cv, int Nreal, int Kpad, int ldc,
    const float* __restrict__ aux0, const float* __restrict__ aux1,
    short* __restrict__ z0, short* __restrict__ z1,
    float* __restrict__ accv)
{
    const int w    = threadIdx.x >> 6;
    const int lane = threadIdx.x & 63;
    const int row0 = ty * 128, col0 = tx * 64;

    const int sr = threadIdx.x >> 3;
    const int sk = (threadIdx.x & 7) * 8;
    const short* Ap = A  + (size_t)(row0 + sr) * Kpad + sk;
    const short* Bp = Bt + (size_t)(col0 + sr) * Kpad + sk;
    const int frow = lane & 15;
    const int fk   = (lane >> 4) * 8;

    f32x4 acc[2][4] = {};

    short8 ra0 = *(const short8*)(Ap);
    short8 ra1 = *(const short8*)(Ap + (size_t)32 * Kpad);
    short8 ra2 = *(const short8*)(Ap + (size_t)64 * Kpad);
    short8 ra3 = *(const short8*)(Ap + (size_t)96 * Kpad);
    short8 rb0 = *(const short8*)(Bp);
    short8 rb1 = *(const short8*)(Bp + (size_t)32 * Kpad);

    for (int k0 = 0; k0 < Kpad; k0 += 64) {
        *(short8*)&As[sr     ][sk] = ra0;
        *(short8*)&As[sr + 32][sk] = ra1;
        *(short8*)&As[sr + 64][sk] = ra2;
        *(short8*)&As[sr + 96][sk] = ra3;
        *(short8*)&Bs[sr     ][sk] = rb0;
        *(short8*)&Bs[sr + 32][sk] = rb1;
        __syncthreads();
        int kn = k0 + 64;
        if (kn < Kpad) {
            ra0 = *(const short8*)(Ap + kn);
            ra1 = *(const short8*)(Ap + (size_t)32 * Kpad + kn);
            ra2 = *(const short8*)(Ap + (size_t)64 * Kpad + kn);
            ra3 = *(const short8*)(Ap + (size_t)96 * Kpad + kn);
            rb0 = *(const short8*)(Bp + kn);
            rb1 = *(const short8*)(Bp + (size_t)32 * Kpad + kn);
        }
#pragma unroll
        for (int kk = 0; kk < 2; ++kk) {
            short8 a0 = *(const short8*)&As[w * 32 +      frow][fk + kk * 32];
            short8 a1 = *(const short8*)&As[w * 32 + 16 + frow][fk + kk * 32];
            short8 b0 = *(const short8*)&Bs[ 0 + frow][fk + kk * 32];
            short8 b1 = *(const short8*)&Bs[16 + frow][fk + kk * 32];
            short8 b2 = *(const short8*)&Bs[32 + frow][fk + kk * 32];
            short8 b3 = *(const short8*)&Bs[48 + frow][fk + kk * 32];
            acc[0][0] = __builtin_amdgcn_mfma_f32_16x16x32_bf16(a0, b0, acc[0][0], 0, 0, 0);
            acc[0][1] = __builtin_amdgcn_mfma_f32_16x16x32_bf16(a0, b1, acc[0][1], 0, 0, 0);
            acc[0][2] = __builtin_amdgcn_mfma_f32_16x16x32_bf16(a0, b2, acc[0][2], 0, 0, 0);
            acc[0][3] = __builtin_amdgcn_mfma_f32_16x16x32_bf16(a0, b3, acc[0][3], 0, 0, 0);
            acc[1][0] = __builtin_amdgcn_mfma_f32_16x16x32_bf16(a1, b0, acc[1][0], 0, 0, 0);
            acc[1][1] = __builtin_amdgcn_mfma_f32_16x16x32_bf16(a1, b1, acc[1][1], 0, 0, 0);
            acc[1][2] = __builtin_amdgcn_mfma_f32_16x16x32_bf16(a1, b2, acc[1][2], 0, 0, 0);
            acc[1][3] = __builtin_amdgcn_mfma_f32_16x16x32_bf16(a1, b3, acc[1][3], 0, 0, 0);
        }
        __syncthreads();
    }

    const int rbase = row0 + w * 32 + (lane >> 4) * 4;

    if (MODE == 3) {
        float kls = 0.f;
#pragma unroll
        for (int mr = 0; mr < 2; ++mr) {
#pragma unroll
            for (int nc = 0; nc < 2; ++nc) {
                int zc = tx * 32 + nc * 16 + frow;
                float bmu = bias[zc];
                float bls = bias2[zc];
#pragma unroll
                for (int j = 0; j < 4; ++j) {
                    int row = rbase + mr * 16 + j;
                    float m = acc[mr][nc][j]     + bmu;
                    float l = acc[mr][nc + 2][j] + bls;
                    float s = expf(l);
                    size_t ei = (size_t)row * 512 + zc;
                    z0[(size_t)row * 832 + zc] = f2bf(m + aux0[ei] * s);
                    z1[ei]                     = f2bf(m + aux1[ei] * s);
                    kls += -0.5f * (1.f + 2.f * l - m * m - expf(2.f * l));
                }
            }
        }
#pragma unroll
        for (int off = 32; off >= 1; off >>= 1) kls += __shfl_xor(kls, off);
        __shared__ float redS[4];
        if (lane == 0) redS[w] = kls;
        __syncthreads();
        if (threadIdx.x == 0) atomicAdd(accv, redS[0] + redS[1] + redS[2] + redS[3]);
        __syncthreads();
        return;
    }

    float fsum = 0.f;
#pragma unroll
    for (int mr = 0; mr < 2; ++mr) {
#pragma unroll
        for (int nc = 0; nc < 4; ++nc) {
            int col = col0 + nc * 16 + frow;
            float bs = bias[col < Nreal ? col : Nreal - 1];
#pragma unroll
            for (int j = 0; j < 4; ++j) {
                float v = acc[mr][nc][j] + bs;
                if (ACT == 1)      v = v > 0.f ? v : 0.f;
                else if (ACT == 2) v = v > 0.f ? v : 0.2f * v;
                else if (ACT == 3) v = 1.f / (1.f + expf(-v));
                int row = rbase + mr * 16 + j;
                if (MODE == 2) {
                    if (col < Nreal) {
                        float d = v - aux0[(size_t)row * 300 + col];
                        fsum += d * d;
                    }
                } else {
                    size_t idx = (size_t)row * ldc + col;
                    if (MODE == 1) ((float*)Cv)[idx] = v;
                    else           ((short*)Cv)[idx] = f2bf(v);
                }
            }
        }
    }
    if (MODE == 2) {
#pragma unroll
        for (int off = 32; off >= 1; off >>= 1) fsum += __shfl_xor(fsum, off);
        __shared__ float redF[4];
        if (lane == 0) redF[w] = fsum;
        __syncthreads();
        if (threadIdx.x == 0) atomicAdd(accv, redF[0] + redF[1] + redF[2] + redF[3]);
        __syncthreads();
    }
}

// ================= the megakernel =================
__global__ __launch_bounds__(256, 2) void mega(MegaArgs g)
{
    __shared__ short As[128][72];
    __shared__ short Bs[64][72];
    float (*T)[65] = (float(*)[65])As;   // transpose tile aliases As (16.6KB < 18.4KB)
    const int bid = blockIdx.x;

    // ---------------- P0: topk+gather | gather_R | weight transpose | zero row0 ----
    for (int u = bid; u < 1093; u += GRID) {
        if (u < 512) {
            int lane = threadIdx.x & 63;
            int row  = u * 4 + (threadIdx.x >> 6);
            const float* pl = g.logits + (size_t)row * NRELS;
            float v[8];
#pragma unroll
            for (int j = 0; j < 8; ++j) v[j] = pl[j * 64 + lane];
            float w[8];
#pragma unroll
            for (int j = 0; j < 8; ++j) w[j] = v[j];
            for (int t = 0; t < 20; ++t) {
                float bv = __builtin_inff(); int bi = 0x7fffffff;
#pragma unroll
                for (int j = 0; j < 8; ++j) {
                    int idx = j * 64 + lane;
                    if (w[j] < bv || (w[j] == bv && idx < bi)) { bv = w[j]; bi = idx; }
                }
#pragma unroll
                for (int off = 32; off >= 1; off >>= 1) {
                    float ov = __shfl_xor(bv, off);
                    int   oi = __shfl_xor(bi, off);
                    if (ov < bv || (ov == bv && oi < bi)) { bv = ov; bi = oi; }
                }
                if ((bi & 63) == lane) w[bi >> 6] = __builtin_inff();
                if (lane == 0) g.dis_idx[row * 20 + t] = bi;
            }
            int t3[3];
#pragma unroll
            for (int j = 0; j < 8; ++j) w[j] = v[j];
            for (int t = 0; t < 3; ++t) {
                float bv = -__builtin_inff(); int bi = 0x7fffffff;
#pragma unroll
                for (int j = 0; j < 8; ++j) {
                    int idx = j * 64 + lane;
                    if (w[j] > bv || (w[j] == bv && idx < bi)) { bv = w[j]; bi = idx; }
                }
#pragma unroll
                for (int off = 32; off >= 1; off >>= 1) {
                    float ov = __shfl_xor(bv, off);
                    int   oi = __shfl_xor(bi, off);
                    if (ov > bv || (ov == bv && oi < bi)) { bv = ov; bi = oi; }
                }
                if ((bi & 63) == lane) w[bi >> 6] = -__builtin_inff();
                t3[t] = bi;
            }
            if (lane == 0) g.top_idx[row] = t3[0];
            int i0 = g.rels[2 * t3[0] + 1];
            int i1 = g.rels[2 * t3[1] + 1];
            int i2 = g.rels[2 * t3[2] + 1];
            const float* r0 = g.rel_dict + (size_t)i0 * FEAT;
            const float* r1 = g.rel_dict + (size_t)i1 * FEAT;
            const float* r2 = g.rel_dict + (size_t)i2 * FEAT;
            short* xd  = g.xcat + (size_t)row * 640;
            short* zd  = g.zcat + (size_t)row * 832;
            float* xfd = g.xf   + (size_t)row * 300;
            for (int c = lane; c < FEAT; c += 64) {
                float a = r0[c];
                float x = a * r1[c] * r2[c];
                xd[c]       = f2bf(x);
                xd[300 + c] = f2bf(a);
                zd[512 + c] = f2bf(a);
                xfd[c]      = x;
            }
            if (lane < 40) xd[600 + lane] = 0;
            if (lane < 20) zd[812 + lane] = 0;
        } else if (u < 640) {
            int lane = threadIdx.x & 63;
            int j = (u - 512) * 4 + (threadIdx.x >> 6);
            int id = g.rels[2 * j + 1];
            const float* src = g.rel_dict + (size_t)id * FEAT;
            for (int c = lane; c < 320; c += 64)
                g.Rb[(size_t)j * 320 + c] = (c < FEAT) ? f2bf(src[c]) : (short)0;
        } else if (u < 1092) {
            // ---- weight transpose: 64x64 LDS tile, coalesced both sides ----
            int uu = u - 640;   // 0..451
            int di = 0;
#pragma unroll
            for (int q = 1; q < 9; ++q) if (uu >= g.wp.d[q].tstart) di = q;
            WDesc w = g.wp.d[di];
            int r  = uu - w.tstart;
            int kt = r % w.tk;
            int nt = r / w.tk;
            int k0 = kt * 64, n0 = nt * 64;
            {
                int kk = threadIdx.x >> 2;
                int c0 = (threadIdx.x & 3) * 16;
                int gk = k0 + kk;
                const float* srow = w.src + (size_t)gk * w.N;
                bool kin = gk < w.K;
#pragma unroll
                for (int j = 0; j < 16; ++j) {
                    int gn = n0 + c0 + j;
                    T[kk][c0 + j] = (kin && gn < w.N) ? srow[gn] : 0.f;
                }
            }
            __syncthreads();
            {
                int nn = threadIdx.x >> 2;
                int c0 = (threadIdx.x & 3) * 16;
                int ns = n0 + nn;
                if (ns < w.Npad || w.ilv) {
                    int nd = w.ilv ? (((ns >> 5) << 6) + w.ilvoff + (ns & 31)) : ns;
                    short* drow = w.dst + (size_t)nd * w.Kpad + k0;
#pragma unroll
                    for (int j = 0; j < 16; ++j)
                        drow[c0 + j] = f2bf(T[c0 + j][nn]);
                }
            }
            __syncthreads();   // T reused next iteration
        } else {
            g.out[2 + threadIdx.x]       = 0.f;
            g.out[2 + 256 + threadIdx.x] = 0.f;
        }
    }
    gsync(g.bar);

    // ---------------- P1: qi1 (64) | fc1 (80) ----------------
    for (int u = bid; u < 144; u += GRID) {
        if (u < 64)
            gemm_core<2,0>(As, Bs, u & 7, u >> 3, g.Rb, g.w_qi1t, g.qi1_b, g.Ehb, 512, 320, 512);
        else {
            int t = u - 64;
            gemm_tile<1,0>(As, Bs, t % 5, t / 5, g.xcat, g.w_fc1t, g.fc1_b, nullptr,
                           g.h1, 300, 640, 320, nullptr, nullptr, nullptr, nullptr, nullptr);
        }
    }
    gsync(g.bar);

    // ---------------- P2: qi2 (64) | mu/ls + sample (256) ----------------
    for (int u = bid; u < 320; u += GRID) {
        if (u < 64)
            gemm_core<2,1>(As, Bs, u & 7, u >> 3, g.Ehb, g.w_qi2t, g.qi2_b, g.E, 512, 512, 512);
        else {
            int t = u - 64;
            gemm_tile<0,3>(As, Bs, t & 15, t >> 4, g.h1, g.w_mulst, g.mu_b, g.ls_b,
                           nullptr, 1024, 320, 0, g.eps1, g.eps2, g.zcat, g.zb, g.acc + 0);
        }
    }
    gsync(g.bar);

    // ---------------- P3: fc3 (80) | qz1 (128) ----------------
    for (int u = bid; u < 208; u += GRID) {
        if (u < 80)
            gemm_tile<1,0>(As, Bs, u % 5, u / 5, g.zcat, g.w_fc3t, g.fc3_b, nullptr,
                           g.h3, 300, 832, 320, nullptr, nullptr, nullptr, nullptr, nullptr);
        else {
            int t = u - 80;
            gemm_tile<2,0>(As, Bs, t & 7, t >> 3, g.zb, g.w_qz1t, g.qz1_b, nullptr,
                           g.t1, 512, 512, 512, nullptr, nullptr, nullptr, nullptr, nullptr);
        }
    }
    gsync(g.bar);

    // ---------------- P4: fc4+recon (80) | qz2 (128) ----------------
    for (int u = bid; u < 208; u += GRID) {
        if (u < 80)
            gemm_tile<3,2>(As, Bs, u % 5, u / 5, g.h3, g.w_fc4t, g.fc4_b, nullptr,
                           nullptr, 300, 320, 0, g.xf, nullptr, nullptr, nullptr, g.acc + 1);
        else {
            int t = u - 80;
            gemm_tile<2,1>(As, Bs, t & 7, t >> 3, g.t1, g.w_qz2t, g.qz2_b, nullptr,
                           g.zp, 512, 512, 512, nullptr, nullptr, nullptr, nullptr, nullptr);
        }
    }
    gsync(g.bar);

    // ---------------- P5: contrastive loss + counter finalize ----------------
    for (int u = bid; u < 512; u += GRID) {
        int lane = threadIdx.x & 63;
        int wv   = threadIdx.x >> 6;
        int r    = u * 4 + wv;
        const float* z = g.zp + (size_t)r * LAT;
        const float4 za = reinterpret_cast<const float4*>(z)[lane * 2 + 0];
        const float4 zb = reinterpret_cast<const float4*>(z)[lane * 2 + 1];
        int ids[21];
        ids[0] = g.top_idx[r];
#pragma unroll
        for (int n = 0; n < 20; ++n) ids[n + 1] = g.dis_idx[r * 20 + n];
        float lg[21];
#pragma unroll
        for (int t = 0; t < 21; ++t) {
            const float* e = g.E + (size_t)ids[t] * LAT;
            const float4 ea = reinterpret_cast<const float4*>(e)[lane * 2 + 0];
            const float4 eb = reinterpret_cast<const float4*>(e)[lane * 2 + 1];
            float d = za.x * ea.x + za.y * ea.y + za.z * ea.z + za.w * ea.w
                    + zb.x * eb.x + zb.y * eb.y + zb.z * eb.z + zb.w * eb.w;
#pragma unroll
            for (int off = 32; off >= 1; off >>= 1) d += __shfl_xor(d, off);
            lg[t] = d / 0.07f;
        }
        float m = lg[0];
#pragma unroll
        for (int t = 1; t < 21; ++t) m = fmaxf(m, lg[t]);
        float s = 0.f;
#pragma unroll
        for (int t = 0; t < 21; ++t) s += expf(lg[t] - m);
        float loss = logf(s) + m - lg[0];
        __shared__ float redC[4];
        if (lane == 0) redC[wv] = loss;
        __syncthreads();
        if (threadIdx.x == 0) {
            atomicAdd(&g.acc[2], redC[0] + redC[1] + redC[2] + redC[3]);
            __threadfence();
            unsigned old = atomicAdd((unsigned*)g.acc + 3, 1u);
            if (old == 511u) {
                __threadfence();
                volatile float* va = g.acc;
                g.out[0] = va[0] + va[1];   // kl + recon
                g.out[1] = va[2];           // csl
            }
        }
        __syncthreads();   // redC reused next iteration
    }
}

// ================= launcher =================
extern "C" void kernel_launch(void* const* d_in, const int* in_sizes, int n_in,
                              void* d_out, int out_size, void* d_ws, size_t ws_size,
                              hipStream_t stream)
{
    const float* logits   = (const float*)d_in[0];
    const int*   rels     = (const int*)  d_in[1];
    const float* rel_dict = (const float*)d_in[2];
    const float* fc1_w    = (const float*)d_in[3];
    const float* fc1_b    = (const float*)d_in[4];
    const float* fc2mu_w  = (const float*)d_in[5];
    const float* fc2mu_b  = (const float*)d_in[6];
    const float* fc2ls_w  = (const float*)d_in[7];
    const float* fc2ls_b  = (const float*)d_in[8];
    const float* fc3_w    = (const float*)d_in[9];
    const float* fc3_b    = (const float*)d_in[10];
    const float* fc4_w    = (const float*)d_in[11];
    const float* fc4_b    = (const float*)d_in[12];
    const float* qi1_w    = (const float*)d_in[13];
    const float* qi1_b    = (const float*)d_in[14];
    const float* qi2_w    = (const float*)d_in[15];
    const float* qi2_b    = (const float*)d_in[16];
    const float* qz1_w    = (const float*)d_in[17];
    const float* qz1_b    = (const float*)d_in[18];
    const float* qz2_w    = (const float*)d_in[19];
    const float* qz2_b    = (const float*)d_in[20];
    const float* eps1     = (const float*)d_in[21];
    const float* eps2     = (const float*)d_in[22];
    float* out = (float*)d_out;

    char* wsb = (char*)d_ws;
    size_t off = 0;
    auto alloc = [&](size_t bytes) -> void* {
        off = (off + 255) & ~(size_t)255;
        void* p = wsb + off;
        off += bytes;
        return p;
    };
    float*    acc = (float*)alloc(1024);             // losses + done counter
    unsigned* bar = (unsigned*)alloc(18 * 256);      // 16 leaves, root, gen
    int*   top_idx = (int*)  alloc((size_t)B * 4);
    int*   dis_idx = (int*)  alloc((size_t)B * 20 * 4);
    short* Rb      = (short*)alloc((size_t)NRELS * 320 * 2);
    short* Ehb     = (short*)alloc((size_t)NRELS * 512 * 2);
    float* E       = (float*)alloc((size_t)NRELS * 512 * 4);
    short* xcat    = (short*)alloc((size_t)B * 640 * 2);
    float* xf      = (float*)alloc((size_t)B * 300 * 4);
    short* h1      = (short*)alloc((size_t)B * 320 * 2);
    short* zcat    = (short*)alloc((size_t)B * 832 * 2);
    short* zb      = (short*)alloc((size_t)B * 512 * 2);
    short* h3      = (short*)alloc((size_t)B * 320 * 2);
    short* t1      = (short*)alloc((size_t)B * 512 * 2);

    short* w_qi1t  = (short*)alloc((size_t)512 * 320 * 2);
    short* w_qi2t  = (short*)alloc((size_t)512 * 512 * 2);
    short* w_fc1t  = (short*)alloc((size_t)320 * 640 * 2);
    short* w_mulst = (short*)alloc((size_t)1024 * 320 * 2);
    short* w_fc3t  = (short*)alloc((size_t)320 * 832 * 2);
    short* w_fc4t  = (short*)alloc((size_t)320 * 320 * 2);
    short* w_qz1t  = (short*)alloc((size_t)512 * 512 * 2);
    short* w_qz2t  = (short*)alloc((size_t)512 * 512 * 2);

    MegaArgs g;
    g.logits = logits; g.rels = rels; g.rel_dict = rel_dict;
    g.fc1_b = fc1_b; g.mu_b = fc2mu_b; g.ls_b = fc2ls_b;
    g.fc3_b = fc3_b; g.fc4_b = fc4_b;
    g.qi1_b = qi1_b; g.qi2_b = qi2_b; g.qz1_b = qz1_b; g.qz2_b = qz2_b;
    g.eps1 = eps1; g.eps2 = eps2;
    g.out = out; g.zp = out + 2 + 512;
    g.acc = acc; g.bar = bar;
    g.top_idx = top_idx; g.dis_idx = dis_idx;
    g.Rb = Rb; g.Ehb = Ehb; g.E = E;
    g.xcat = xcat; g.xf = xf;
    g.h1 = h1; g.zcat = zcat; g.zb = zb; g.h3 = h3; g.t1 = t1;
    g.w_qi1t = w_qi1t; g.w_qi2t = w_qi2t; g.w_fc1t = w_fc1t; g.w_mulst = w_mulst;
    g.w_fc3t = w_fc3t; g.w_fc4t = w_fc4t; g.w_qz1t = w_qz1t; g.w_qz2t = w_qz2t;

    //           src      dst      K    N   Kpad  Npad ilv off tstart tk
    g.wp.d[0] = {qi1_w,   w_qi1t,  300, 512, 320,  512, 0, 0,    0,  5};
    g.wp.d[1] = {qi2_w,   w_qi2t,  512, 512, 512,  512, 0, 0,   40,  8};
    g.wp.d[2] = {fc1_w,   w_fc1t,  600, 300, 640,  320, 0, 0,  104, 10};
    g.wp.d[3] = {fc2mu_w, w_mulst, 300, 512, 320, 1024, 1, 0,  154,  5};
    g.wp.d[4] = {fc2ls_w, w_mulst, 300, 512, 320, 1024, 1, 32, 194,  5};
    g.wp.d[5] = {fc3_w,   w_fc3t,  812, 300, 832,  320, 0, 0,  234, 13};
    g.wp.d[6] = {fc4_w,   w_fc4t,  300, 300, 320,  320, 0, 0,  299,  5};
    g.wp.d[7] = {qz1_w,   w_qz1t,  512, 512, 512,  512, 0, 0,  324,  8};
    g.wp.d[8] = {qz2_w,   w_qz2t,  512, 512, 512,  512, 0, 0,  388,  8};

    // zero losses + done counter + all barrier lines (ws is poisoned before timing)
    hipMemsetAsync(acc, 0, 1024 + 18 * 256, stream);
    mega<<<GRID, 256, 0, stream>>>(g);
}

// Round 10
// 209.387 us; speedup vs baseline: 1.4271x; 1.4271x over previous
//
#include <hip/hip_runtime.h>
#include <math.h>

#define B      2048
#define NRELS  512
#define FEAT   300
#define LAT    512

typedef __attribute__((ext_vector_type(8))) short short8;
typedef __attribute__((ext_vector_type(4))) float f32x4;

__device__ inline short f2bf(float f) {
    union { float f; unsigned u; } v; v.f = f;
    unsigned u = v.u;
    u += 0x7fffu + ((u >> 16) & 1u);   // RNE
    return (short)(u >> 16);
}

// ================= weight descriptors (transpose tiles) =================
struct WDesc { const float* src; short* dst; int K, N, Kpad, Npad, tstart, tk; };
struct WPack { WDesc d[9]; };

struct Args {
    const float* logits; const int* rels; const float* rel_dict;
    const float* fc1_b; const float* mu_b; const float* ls_b;
    const float* fc3_b; const float* fc4_b;
    const float* qi1_b; const float* qi2_b; const float* qz1_b; const float* qz2_b;
    const float* eps1;  const float* eps2;
    float* out; float* zp;
    float* acc;          // [0]=kl [1]=recon [2]=csl, ((unsigned*)acc)[3]=done
    int* top_idx; int* dis_idx;
    short* Rb; short* Ehb; float* E;
    short* xcat; float* xf;
    short* h1; short* zcat; short* zb; short* h3; short* t1;
    const short* w_qi1t; const short* w_qi2t; const short* w_fc1t; const short* w_mulst;
    const short* w_fc3t; const short* w_fc4t; const short* w_qz1t; const short* w_qz2t;
    WPack wp;
};

// ================= A-slab stage: 16 rows x Kpad into LDS (once per layer) ========
__device__ inline void stage_A(short (&As)[16][840], const short* A, int lda, int r0, int Kpad)
{
    __syncthreads();   // drain prior layer's stores + LDS uses
    int chunks = Kpad >> 3;
    for (int idx = threadIdx.x; idx < 16 * chunks; idx += 256) {
        int row = idx / chunks;
        int ko  = (idx - row * chunks) * 8;
        *(short8*)&As[row][ko] = *(const short8*)(A + (size_t)(r0 + row) * lda + ko);
    }
    __syncthreads();
}

// ================= slab GEMM: out rows r0..r0+16 = act(A(16xK) @ Wt^T + bias) ====
// 4 waves; wave w owns cols w*16 of each 64-col tile. MODE: 0 bf16 store,
// 1 f32 store, 2 fc4 sigmoid+recon fuse, 3 mu/ls dual + sample fuse.
template<int ACT, int MODE>
__device__ void slab_gemm(short (&As)[16][840], short (&Bs)[128][72],
                          int r0, const short* __restrict__ Wt,
                          const float* __restrict__ bias, const float* __restrict__ bias2,
                          void* __restrict__ Cv, int Nreal, int Ntiles, int Kpad, int ldc,
                          const float* __restrict__ aux0, const float* __restrict__ aux1,
                          short* __restrict__ z0, short* __restrict__ z1,
                          float* __restrict__ accv)
{
    const int wv   = threadIdx.x >> 6;
    const int lane = threadIdx.x & 63;
    const int frow = lane & 15;
    const int fk   = (lane >> 4) * 8;
    const int sr   = threadIdx.x >> 3;        // 0..31
    const int sk   = (threadIdx.x & 7) * 8;   // 0..56
    float redacc = 0.f;

    for (int bx = 0; bx < Ntiles; ++bx) {
        const short* Bp  = Wt + (size_t)(bx * 64 + sr) * Kpad + sk;
        const short* Bp2 = Wt + (size_t)(512 + bx * 64 + sr) * Kpad + sk;  // MODE3 (ls)
        f32x4 acc0 = {0,0,0,0}, acc1 = {0,0,0,0};

        short8 b0 = *(const short8*)Bp;
        short8 b1 = *(const short8*)(Bp + (size_t)32 * Kpad);
        short8 c0{}, c1{};
        if (MODE == 3) {
            c0 = *(const short8*)Bp2;
            c1 = *(const short8*)(Bp2 + (size_t)32 * Kpad);
        }
        for (int k0 = 0; k0 < Kpad; k0 += 64) {
            *(short8*)&Bs[sr     ][sk] = b0;
            *(short8*)&Bs[sr + 32][sk] = b1;
            if (MODE == 3) {
                *(short8*)&Bs[sr + 64][sk] = c0;
                *(short8*)&Bs[sr + 96][sk] = c1;
            }
            __syncthreads();
            int kn = k0 + 64;
            if (kn < Kpad) {   // reg-prefetch next K-chunk under MFMA phase
                b0 = *(const short8*)(Bp + kn);
                b1 = *(const short8*)(Bp + (size_t)32 * Kpad + kn);
                if (MODE == 3) {
                    c0 = *(const short8*)(Bp2 + kn);
                    c1 = *(const short8*)(Bp2 + (size_t)32 * Kpad + kn);
                }
            }
#pragma unroll
            for (int kk = 0; kk < 2; ++kk) {
                short8 af = *(const short8*)&As[frow][k0 + fk + kk * 32];
                short8 bf = *(const short8*)&Bs[wv * 16 + frow][fk + kk * 32];
                acc0 = __builtin_amdgcn_mfma_f32_16x16x32_bf16(af, bf, acc0, 0, 0, 0);
                if (MODE == 3) {
                    short8 cf = *(const short8*)&Bs[64 + wv * 16 + frow][fk + kk * 32];
                    acc1 = __builtin_amdgcn_mfma_f32_16x16x32_bf16(af, cf, acc1, 0, 0, 0);
                }
            }
            __syncthreads();
        }

        int col = bx * 64 + wv * 16 + frow;
        if (MODE == 3) {
            float bmu = bias[col], bls = bias2[col];
#pragma unroll
            for (int j = 0; j < 4; ++j) {
                int row = r0 + (lane >> 4) * 4 + j;
                float m = acc0[j] + bmu;
                float l = acc1[j] + bls;
                float s = expf(l);
                size_t ei = (size_t)row * 512 + col;
                z0[(size_t)row * 832 + col] = f2bf(m + aux0[ei] * s);
                z1[ei]                      = f2bf(m + aux1[ei] * s);
                redacc += -0.5f * (1.f + 2.f * l - m * m - expf(2.f * l));
            }
        } else {
            float bs = bias[col < Nreal ? col : Nreal - 1];
#pragma unroll
            for (int j = 0; j < 4; ++j) {
                int row = r0 + (lane >> 4) * 4 + j;
                float v = acc0[j] + bs;
                if (ACT == 1)      v = v > 0.f ? v : 0.f;
                else if (ACT == 2) v = v > 0.f ? v : 0.2f * v;
                else if (ACT == 3) v = 1.f / (1.f + expf(-v));
                if (MODE == 2) {
                    if (col < Nreal) {
                        float d = v - aux0[(size_t)row * 300 + col];
                        redacc += d * d;
                    }
                } else {
                    size_t idx = (size_t)row * ldc + col;
                    if (MODE == 1) ((float*)Cv)[idx] = v;
                    else           ((short*)Cv)[idx] = f2bf(v);
                }
            }
        }
    }

    if (MODE == 2 || MODE == 3) {   // one atomic per block
#pragma unroll
        for (int off = 32; off >= 1; off >>= 1) redacc += __shfl_xor(redacc, off);
        __shared__ float red[4];
        if (lane == 0) red[wv] = redacc;
        __syncthreads();
        if (threadIdx.x == 0) atomicAdd(accv, red[0] + red[1] + red[2] + red[3]);
        __syncthreads();
    }
}

// ================= DISPATCH 1: prep =================
// blocks [0,512): topk + gather (4 batch rows each)
// blocks [512,964): weight transpose (452 tiles)
// block 964: zero acc + z_rel row 0
__global__ __launch_bounds__(256) void prep(Args g)
{
    __shared__ float T[64][65];
    const int bid = blockIdx.x;

    if (bid < 512) {
        int lane = threadIdx.x & 63;
        int row  = bid * 4 + (threadIdx.x >> 6);
        const float* pl = g.logits + (size_t)row * NRELS;
        float v[8];
#pragma unroll
        for (int j = 0; j < 8; ++j) v[j] = pl[j * 64 + lane];
        float w[8];
#pragma unroll
        for (int j = 0; j < 8; ++j) w[j] = v[j];
        for (int t = 0; t < 20; ++t) {
            float bv = __builtin_inff(); int bi = 0x7fffffff;
#pragma unroll
            for (int j = 0; j < 8; ++j) {
                int idx = j * 64 + lane;
                if (w[j] < bv || (w[j] == bv && idx < bi)) { bv = w[j]; bi = idx; }
            }
#pragma unroll
            for (int off = 32; off >= 1; off >>= 1) {
                float ov = __shfl_xor(bv, off);
                int   oi = __shfl_xor(bi, off);
                if (ov < bv || (ov == bv && oi < bi)) { bv = ov; bi = oi; }
            }
            if ((bi & 63) == lane) w[bi >> 6] = __builtin_inff();
            if (lane == 0) g.dis_idx[row * 20 + t] = bi;
        }
        int t3[3];
#pragma unroll
        for (int j = 0; j < 8; ++j) w[j] = v[j];
        for (int t = 0; t < 3; ++t) {
            float bv = -__builtin_inff(); int bi = 0x7fffffff;
#pragma unroll
            for (int j = 0; j < 8; ++j) {
                int idx = j * 64 + lane;
                if (w[j] > bv || (w[j] == bv && idx < bi)) { bv = w[j]; bi = idx; }
            }
#pragma unroll
            for (int off = 32; off >= 1; off >>= 1) {
                float ov = __shfl_xor(bv, off);
                int   oi = __shfl_xor(bi, off);
                if (ov > bv || (ov == bv && oi < bi)) { bv = ov; bi = oi; }
            }
            if ((bi & 63) == lane) w[bi >> 6] = -__builtin_inff();
            t3[t] = bi;
        }
        if (lane == 0) g.top_idx[row] = t3[0];
        int i0 = g.rels[2 * t3[0] + 1];
        int i1 = g.rels[2 * t3[1] + 1];
        int i2 = g.rels[2 * t3[2] + 1];
        const float* r0p = g.rel_dict + (size_t)i0 * FEAT;
        const float* r1p = g.rel_dict + (size_t)i1 * FEAT;
        const float* r2p = g.rel_dict + (size_t)i2 * FEAT;
        short* xd  = g.xcat + (size_t)row * 640;
        short* zd  = g.zcat + (size_t)row * 832;
        float* xfd = g.xf   + (size_t)row * 300;
        for (int c = lane; c < FEAT; c += 64) {
            float a = r0p[c];
            float x = a * r1p[c] * r2p[c];
            xd[c]       = f2bf(x);
            xd[300 + c] = f2bf(a);
            zd[512 + c] = f2bf(a);
            xfd[c]      = x;
        }
        if (lane < 40) xd[600 + lane] = 0;
        if (lane < 20) zd[812 + lane] = 0;
    } else if (bid < 964) {
        // weight transpose: 64x64 LDS tile, coalesced both sides, zero-padded
        int uu = bid - 512;   // 0..451
        int di = 0;
#pragma unroll
        for (int q = 1; q < 9; ++q) if (uu >= g.wp.d[q].tstart) di = q;
        WDesc w = g.wp.d[di];
        int r  = uu - w.tstart;
        int kt = r % w.tk;
        int nt = r / w.tk;
        int k0 = kt * 64, n0 = nt * 64;
        {
            int kk = threadIdx.x >> 2;
            int c0 = (threadIdx.x & 3) * 16;
            int gk = k0 + kk;
            const float* srow = w.src + (size_t)gk * w.N;
            bool kin = gk < w.K;
#pragma unroll
            for (int j = 0; j < 16; ++j) {
                int gn = n0 + c0 + j;
                T[kk][c0 + j] = (kin && gn < w.N) ? srow[gn] : 0.f;
            }
        }
        __syncthreads();
        {
            int nn = threadIdx.x >> 2;
            int c0 = (threadIdx.x & 3) * 16;
            int ns = n0 + nn;
            if (ns < w.Npad) {
                short* drow = w.dst + (size_t)ns * w.Kpad + k0;
#pragma unroll
                for (int j = 0; j < 16; ++j)
                    drow[c0 + j] = f2bf(T[c0 + j][nn]);
            }
        }
    } else {
        if (threadIdx.x < 4) ((unsigned*)g.acc)[threadIdx.x] = 0u;
        g.out[2 + threadIdx.x]       = 0.f;
        g.out[2 + 256 + threadIdx.x] = 0.f;
    }
}

// ================= DISPATCH 2: batch chain (blocks 0-127) | E-chain (128-159) ===
__global__ __launch_bounds__(256) void mainker(Args g)
{
    __shared__ short As[16][840];
    __shared__ short Bs[128][72];

    if (blockIdx.x < 128) {
        const int r0 = blockIdx.x * 16;
        stage_A(As, g.xcat, 640, r0, 640);
        slab_gemm<1,0>(As, Bs, r0, g.w_fc1t, g.fc1_b, nullptr, (void*)g.h1,
                       300, 5, 640, 320, nullptr, nullptr, nullptr, nullptr, nullptr);
        stage_A(As, g.h1, 320, r0, 320);
        slab_gemm<0,3>(As, Bs, r0, g.w_mulst, g.mu_b, g.ls_b, nullptr,
                       512, 8, 320, 0, g.eps1, g.eps2, g.zcat, g.zb, g.acc + 0);
        stage_A(As, g.zcat, 832, r0, 832);
        slab_gemm<1,0>(As, Bs, r0, g.w_fc3t, g.fc3_b, nullptr, (void*)g.h3,
                       300, 5, 832, 320, nullptr, nullptr, nullptr, nullptr, nullptr);
        stage_A(As, g.h3, 320, r0, 320);
        slab_gemm<3,2>(As, Bs, r0, g.w_fc4t, g.fc4_b, nullptr, nullptr,
                       300, 5, 320, 0, g.xf, nullptr, nullptr, nullptr, g.acc + 1);
        stage_A(As, g.zb, 512, r0, 512);
        slab_gemm<2,0>(As, Bs, r0, g.w_qz1t, g.qz1_b, nullptr, (void*)g.t1,
                       512, 8, 512, 512, nullptr, nullptr, nullptr, nullptr, nullptr);
        stage_A(As, g.t1, 512, r0, 512);
        slab_gemm<2,1>(As, Bs, r0, g.w_qz2t, g.qz2_b, nullptr, (void*)g.zp,
                       512, 8, 512, 512, nullptr, nullptr, nullptr, nullptr, nullptr);
    } else {
        // E-chain: 16 rels per block (gather -> qi1 -> qi2); weights transposed in prep
        const int r0 = (blockIdx.x - 128) * 16;
        for (int idx = threadIdx.x; idx < 16 * 320; idx += 256) {
            int row = idx / 320, c = idx - row * 320;
            int id = g.rels[2 * (r0 + row) + 1];
            g.Rb[(size_t)(r0 + row) * 320 + c] =
                (c < FEAT) ? f2bf(g.rel_dict[(size_t)id * FEAT + c]) : (short)0;
        }
        stage_A(As, g.Rb, 320, r0, 320);
        slab_gemm<2,0>(As, Bs, r0, g.w_qi1t, g.qi1_b, nullptr, (void*)g.Ehb,
                       512, 8, 320, 512, nullptr, nullptr, nullptr, nullptr, nullptr);
        stage_A(As, g.Ehb, 512, r0, 512);
        slab_gemm<2,1>(As, Bs, r0, g.w_qi2t, g.qi2_b, nullptr, (void*)g.E,
                       512, 8, 512, 512, nullptr, nullptr, nullptr, nullptr, nullptr);
    }
}

// ================= DISPATCH 3: contrastive loss + finalize =================
__global__ __launch_bounds__(256) void cslker(Args g)
{
    int lane = threadIdx.x & 63;
    int wv   = threadIdx.x >> 6;
    int r    = blockIdx.x * 4 + wv;
    const float* z = g.zp + (size_t)r * LAT;
    const float4 za = reinterpret_cast<const float4*>(z)[lane * 2 + 0];
    const float4 zb = reinterpret_cast<const float4*>(z)[lane * 2 + 1];

    int ids[21];
    ids[0] = g.top_idx[r];
#pragma unroll
    for (int n = 0; n < 20; ++n) ids[n + 1] = g.dis_idx[r * 20 + n];

    float lg[21];
#pragma unroll
    for (int t = 0; t < 21; ++t) {
        const float* e = g.E + (size_t)ids[t] * LAT;
        const float4 ea = reinterpret_cast<const float4*>(e)[lane * 2 + 0];
        const float4 eb = reinterpret_cast<const float4*>(e)[lane * 2 + 1];
        float d = za.x * ea.x + za.y * ea.y + za.z * ea.z + za.w * ea.w
                + zb.x * eb.x + zb.y * eb.y + zb.z * eb.z + zb.w * eb.w;
#pragma unroll
        for (int off = 32; off >= 1; off >>= 1) d += __shfl_xor(d, off);
        lg[t] = d / 0.07f;
    }
    float m = lg[0];
#pragma unroll
    for (int t = 1; t < 21; ++t) m = fmaxf(m, lg[t]);
    float s = 0.f;
#pragma unroll
    for (int t = 0; t < 21; ++t) s += expf(lg[t] - m);
    float loss = logf(s) + m - lg[0];

    __shared__ float red[4];
    if (lane == 0) red[wv] = loss;
    __syncthreads();
    if (threadIdx.x == 0) {
        atomicAdd(&g.acc[2], red[0] + red[1] + red[2] + red[3]);
        __threadfence();
        unsigned old = atomicAdd((unsigned*)g.acc + 3, 1u);
        if (old == (unsigned)(gridDim.x - 1)) {
            __threadfence();
            volatile float* va = g.acc;
            g.out[0] = va[0] + va[1];   // kl + recon
            g.out[1] = va[2];           // csl
        }
    }
}

// ================= launcher =================
extern "C" void kernel_launch(void* const* d_in, const int* in_sizes, int n_in,
                              void* d_out, int out_size, void* d_ws, size_t ws_size,
                              hipStream_t stream)
{
    const float* logits   = (const float*)d_in[0];
    const int*   rels     = (const int*)  d_in[1];
    const float* rel_dict = (const float*)d_in[2];
    const float* fc1_w    = (const float*)d_in[3];
    const float* fc1_b    = (const float*)d_in[4];
    const float* fc2mu_w  = (const float*)d_in[5];
    const float* fc2mu_b  = (const float*)d_in[6];
    const float* fc2ls_w  = (const float*)d_in[7];
    const float* fc2ls_b  = (const float*)d_in[8];
    const float* fc3_w    = (const float*)d_in[9];
    const float* fc3_b    = (const float*)d_in[10];
    const float* fc4_w    = (const float*)d_in[11];
    const float* fc4_b    = (const float*)d_in[12];
    const float* qi1_w    = (const float*)d_in[13];
    const float* qi1_b    = (const float*)d_in[14];
    const float* qi2_w    = (const float*)d_in[15];
    const float* qi2_b    = (const float*)d_in[16];
    const float* qz1_w    = (const float*)d_in[17];
    const float* qz1_b    = (const float*)d_in[18];
    const float* qz2_w    = (const float*)d_in[19];
    const float* qz2_b    = (const float*)d_in[20];
    const float* eps1     = (const float*)d_in[21];
    const float* eps2     = (const float*)d_in[22];
    float* out = (float*)d_out;

    char* wsb = (char*)d_ws;
    size_t off = 0;
    auto alloc = [&](size_t bytes) -> void* {
        off = (off + 255) & ~(size_t)255;
        void* p = wsb + off;
        off += bytes;
        return p;
    };
    float* acc     = (float*)alloc(256);
    int*   top_idx = (int*)  alloc((size_t)B * 4);
    int*   dis_idx = (int*)  alloc((size_t)B * 20 * 4);
    short* Rb      = (short*)alloc((size_t)NRELS * 320 * 2);
    short* Ehb     = (short*)alloc((size_t)NRELS * 512 * 2);
    float* E       = (float*)alloc((size_t)NRELS * 512 * 4);
    short* xcat    = (short*)alloc((size_t)B * 640 * 2);
    float* xf      = (float*)alloc((size_t)B * 300 * 4);
    short* h1      = (short*)alloc((size_t)B * 320 * 2);
    short* zcat    = (short*)alloc((size_t)B * 832 * 2);
    short* zb      = (short*)alloc((size_t)B * 512 * 2);
    short* h3      = (short*)alloc((size_t)B * 320 * 2);
    short* t1      = (short*)alloc((size_t)B * 512 * 2);

    short* w_qi1t  = (short*)alloc((size_t)512 * 320 * 2);
    short* w_qi2t  = (short*)alloc((size_t)512 * 512 * 2);
    short* w_fc1t  = (short*)alloc((size_t)320 * 640 * 2);
    short* w_mulst = (short*)alloc((size_t)1024 * 320 * 2);  // mu rows 0-511, ls rows 512-1023
    short* w_fc3t  = (short*)alloc((size_t)320 * 832 * 2);
    short* w_fc4t  = (short*)alloc((size_t)320 * 320 * 2);
    short* w_qz1t  = (short*)alloc((size_t)512 * 512 * 2);
    short* w_qz2t  = (short*)alloc((size_t)512 * 512 * 2);

    Args g;
    g.logits = logits; g.rels = rels; g.rel_dict = rel_dict;
    g.fc1_b = fc1_b; g.mu_b = fc2mu_b; g.ls_b = fc2ls_b;
    g.fc3_b = fc3_b; g.fc4_b = fc4_b;
    g.qi1_b = qi1_b; g.qi2_b = qi2_b; g.qz1_b = qz1_b; g.qz2_b = qz2_b;
    g.eps1 = eps1; g.eps2 = eps2;
    g.out = out; g.zp = out + 2 + 512;
    g.acc = acc;
    g.top_idx = top_idx; g.dis_idx = dis_idx;
    g.Rb = Rb; g.Ehb = Ehb; g.E = E;
    g.xcat = xcat; g.xf = xf;
    g.h1 = h1; g.zcat = zcat; g.zb = zb; g.h3 = h3; g.t1 = t1;
    g.w_qi1t = w_qi1t; g.w_qi2t = w_qi2t; g.w_fc1t = w_fc1t; g.w_mulst = w_mulst;
    g.w_fc3t = w_fc3t; g.w_fc4t = w_fc4t; g.w_qz1t = w_qz1t; g.w_qz2t = w_qz2t;

    //           src      dst                 K    N   Kpad  Npad tstart tk
    g.wp.d[0] = {qi1_w,   w_qi1t,            300, 512, 320,  512,    0,  5};   // 40
    g.wp.d[1] = {qi2_w,   w_qi2t,            512, 512, 512,  512,   40,  8};   // 64
    g.wp.d[2] = {fc1_w,   w_fc1t,            600, 300, 640,  320,  104, 10};   // 50
    g.wp.d[3] = {fc2mu_w, w_mulst,           300, 512, 320,  512,  154,  5};   // 40
    g.wp.d[4] = {fc2ls_w, w_mulst + 512*320, 300, 512, 320,  512,  194,  5};   // 40
    g.wp.d[5] = {fc3_w,   w_fc3t,            812, 300, 832,  320,  234, 13};   // 65
    g.wp.d[6] = {fc4_w,   w_fc4t,            300, 300, 320,  320,  299,  5};   // 25
    g.wp.d[7] = {qz1_w,   w_qz1t,            512, 512, 512,  512,  324,  8};   // 64
    g.wp.d[8] = {qz2_w,   w_qz2t,            512, 512, 512,  512,  388,  8};   // 64 -> 452

    prep   <<<965, 256, 0, stream>>>(g);
    mainker<<<160, 256, 0, stream>>>(g);
    cslker <<<512, 256, 0, stream>>>(g);
}

// Round 11
// 97.916 us; speedup vs baseline: 3.0516x; 2.1384x over previous
//
#include <hip/hip_runtime.h>
#include <math.h>

#define B      2048
#define NRELS  512
#define FEAT   300
#define LAT    512

typedef __attribute__((ext_vector_type(8))) short short8;
typedef __attribute__((ext_vector_type(4))) float f32x4;

__device__ inline short f2bf(float f) {
    union { float f; unsigned u; } v; v.f = f;
    unsigned u = v.u;
    u += 0x7fffu + ((u >> 16) & 1u);   // RNE
    return (short)(u >> 16);
}

// ================= weight descriptors (transpose tiles) =================
struct WDesc { const float* src; short* dst; int K, N, Kpad, Npad, ilv, ilvoff, tstart, tk; };
struct WPack { WDesc d[9]; };

// ================= STAGE 0: topk/gather | gather_R | coalesced transpose | zeros =====
__global__ __launch_bounds__(256) void stage0(WPack p,
                                              const float* __restrict__ logits,
                                              const int* __restrict__ rels,
                                              const float* __restrict__ rel_dict,
                                              int* __restrict__ top_idx,
                                              int* __restrict__ dis_idx,
                                              short* __restrict__ xcat,  // [B][640]
                                              float* __restrict__ xf,    // [B][300]
                                              short* __restrict__ zcat,  // [B][832]
                                              short* __restrict__ Rb,    // [512][320]
                                              float* __restrict__ acc,   // [4]
                                              float* __restrict__ out)
{
    __shared__ float T[64][65];
    const int bid = blockIdx.x;
    if (bid < 512) {
        // ---- topk + gather, 4 rows/block ----
        if (bid == 0 && threadIdx.x >= 252) ((unsigned*)acc)[threadIdx.x - 252] = 0u;
        int lane = threadIdx.x & 63;
        int row  = bid * 4 + (threadIdx.x >> 6);
        const float* pl = logits + (size_t)row * NRELS;
        float v[8];
#pragma unroll
        for (int j = 0; j < 8; ++j) v[j] = pl[j * 64 + lane];
        float w[8];
#pragma unroll
        for (int j = 0; j < 8; ++j) w[j] = v[j];
        for (int t = 0; t < 20; ++t) {
            float bv = __builtin_inff(); int bi = 0x7fffffff;
#pragma unroll
            for (int j = 0; j < 8; ++j) {
                int idx = j * 64 + lane;
                if (w[j] < bv || (w[j] == bv && idx < bi)) { bv = w[j]; bi = idx; }
            }
#pragma unroll
            for (int off = 32; off >= 1; off >>= 1) {
                float ov = __shfl_xor(bv, off);
                int   oi = __shfl_xor(bi, off);
                if (ov < bv || (ov == bv && oi < bi)) { bv = ov; bi = oi; }
            }
            if ((bi & 63) == lane) w[bi >> 6] = __builtin_inff();
            if (lane == 0) dis_idx[row * 20 + t] = bi;
        }
        int t3[3];
#pragma unroll
        for (int j = 0; j < 8; ++j) w[j] = v[j];
        for (int t = 0; t < 3; ++t) {
            float bv = -__builtin_inff(); int bi = 0x7fffffff;
#pragma unroll
            for (int j = 0; j < 8; ++j) {
                int idx = j * 64 + lane;
                if (w[j] > bv || (w[j] == bv && idx < bi)) { bv = w[j]; bi = idx; }
            }
#pragma unroll
            for (int off = 32; off >= 1; off >>= 1) {
                float ov = __shfl_xor(bv, off);
                int   oi = __shfl_xor(bi, off);
                if (ov > bv || (ov == bv && oi < bi)) { bv = ov; bi = oi; }
            }
            if ((bi & 63) == lane) w[bi >> 6] = -__builtin_inff();
            t3[t] = bi;
        }
        if (lane == 0) top_idx[row] = t3[0];
        int i0 = rels[2 * t3[0] + 1];
        int i1 = rels[2 * t3[1] + 1];
        int i2 = rels[2 * t3[2] + 1];
        const float* r0 = rel_dict + (size_t)i0 * FEAT;
        const float* r1 = rel_dict + (size_t)i1 * FEAT;
        const float* r2 = rel_dict + (size_t)i2 * FEAT;
        short* xd  = xcat + (size_t)row * 640;
        short* zd  = zcat + (size_t)row * 832;
        float* xfd = xf   + (size_t)row * 300;
        for (int c = lane; c < FEAT; c += 64) {
            float a = r0[c];
            float x = a * r1[c] * r2[c];
            xd[c]       = f2bf(x);
            xd[300 + c] = f2bf(a);
            zd[512 + c] = f2bf(a);
            xfd[c]      = x;
        }
        if (lane < 40) xd[600 + lane] = 0;
        if (lane < 20) zd[812 + lane] = 0;
    } else if (bid < 640) {
        // ---- gather_R, 4 rels/block ----
        int lane = threadIdx.x & 63;
        int j = (bid - 512) * 4 + (threadIdx.x >> 6);
        int id = rels[2 * j + 1];
        const float* src = rel_dict + (size_t)id * FEAT;
        for (int c = lane; c < 320; c += 64)
            Rb[(size_t)j * 320 + c] = (c < FEAT) ? f2bf(src[c]) : (short)0;
    } else if (bid < 1092) {
        // ---- coalesced weight transpose: 64x64 LDS tile ----
        int uu = bid - 640;   // 0..451
        int di = 0;
#pragma unroll
        for (int q = 1; q < 9; ++q) if (uu >= p.d[q].tstart) di = q;
        WDesc w = p.d[di];
        int r  = uu - w.tstart;
        int kt = r % w.tk;          // k-tile
        int nt = r / w.tk;          // n-tile (source cols)
        int k0 = kt * 64, n0 = nt * 64;
        {   // load: thread reads 16 consecutive f32 of source row (k0 + t/4)
            int kk = threadIdx.x >> 2;
            int c0 = (threadIdx.x & 3) * 16;
            int gk = k0 + kk;
            const float* srow = w.src + (size_t)gk * w.N;
            bool kin = gk < w.K;
#pragma unroll
            for (int j = 0; j < 16; ++j) {
                int gn = n0 + c0 + j;
                T[kk][c0 + j] = (kin && gn < w.N) ? srow[gn] : 0.f;
            }
        }
        __syncthreads();
        {   // write: thread writes 16 consecutive bf16 of dst row map(n0 + t/4)
            int nn = threadIdx.x >> 2;
            int c0 = (threadIdx.x & 3) * 16;
            int ns = n0 + nn;
            int nd = w.ilv ? (((ns >> 5) << 6) + w.ilvoff + (ns & 31)) : ns;
            short* drow = w.dst + (size_t)nd * w.Kpad + k0;
#pragma unroll
            for (int j = 0; j < 16; ++j)
                drow[c0 + j] = f2bf(T[c0 + j][nn]);
        }
    } else {
        // ---- zero z_rel row 0 ----
        out[2 + threadIdx.x]       = 0.f;
        out[2 + 256 + threadIdx.x] = 0.f;
    }
}

// ================= MFMA GEMM core (64x64 tile, BK=64, reg prefetch) =================
// MODE: 0 = store bf16, 1 = store f32, 2 = fc4 sigmoid+recon fuse, 3 = mu/ls sample fuse
template<int ACT, int MODE>   // ACT: 0 none, 1 relu, 2 leaky0.2, 3 sigmoid
__device__ __attribute__((always_inline)) void gemm_core(
    short (&As)[64][72], short (&Bs)[64][72],
    int bx, int by,
    const short* __restrict__ A, const short* __restrict__ Bt,
    const float* __restrict__ bias, const float* __restrict__ bias2,
    void* __restrict__ Cv, int Nreal, int Kpad, int ldc,
    const float* __restrict__ aux0, const float* __restrict__ aux1,
    short* __restrict__ z0, short* __restrict__ z1,
    float* __restrict__ accv)
{
    const int wave = threadIdx.x >> 6;
    const int lane = threadIdx.x & 63;
    const int row0 = by * 64;
    const int col0 = bx * 64;

    const int srow = threadIdx.x >> 3;
    const int sk   = (threadIdx.x & 7) * 8;
    const short* Ap0 = A  + (size_t)(row0 + srow)      * Kpad + sk;
    const short* Ap1 = A  + (size_t)(row0 + srow + 32) * Kpad + sk;
    const short* Bp0 = Bt + (size_t)(col0 + srow)      * Kpad + sk;
    const short* Bp1 = Bt + (size_t)(col0 + srow + 32) * Kpad + sk;

    const int frow = lane & 15;
    const int fk   = (lane >> 4) * 8;

    f32x4 acc0 = {0,0,0,0}, acc1 = {0,0,0,0}, acc2 = {0,0,0,0}, acc3 = {0,0,0,0};

    short8 a0 = *(const short8*)Ap0;
    short8 a1 = *(const short8*)Ap1;
    short8 b0 = *(const short8*)Bp0;
    short8 b1 = *(const short8*)Bp1;

    for (int k0 = 0; k0 < Kpad; k0 += 64) {
        *(short8*)&As[srow][sk]      = a0;
        *(short8*)&As[srow + 32][sk] = a1;
        *(short8*)&Bs[srow][sk]      = b0;
        *(short8*)&Bs[srow + 32][sk] = b1;
        __syncthreads();
        int kn = k0 + 64;
        if (kn < Kpad) {
            a0 = *(const short8*)(Ap0 + kn);
            a1 = *(const short8*)(Ap1 + kn);
            b0 = *(const short8*)(Bp0 + kn);
            b1 = *(const short8*)(Bp1 + kn);
        }
#pragma unroll
        for (int kk = 0; kk < 2; ++kk) {
            short8 af  = *(const short8*)&As[wave * 16 + frow][fk + kk * 32];
            short8 bf0 = *(const short8*)&Bs[ 0 + frow][fk + kk * 32];
            short8 bf1 = *(const short8*)&Bs[16 + frow][fk + kk * 32];
            short8 bf2 = *(const short8*)&Bs[32 + frow][fk + kk * 32];
            short8 bf3 = *(const short8*)&Bs[48 + frow][fk + kk * 32];
            acc0 = __builtin_amdgcn_mfma_f32_16x16x32_bf16(af, bf0, acc0, 0, 0, 0);
            acc1 = __builtin_amdgcn_mfma_f32_16x16x32_bf16(af, bf1, acc1, 0, 0, 0);
            acc2 = __builtin_amdgcn_mfma_f32_16x16x32_bf16(af, bf2, acc2, 0, 0, 0);
            acc3 = __builtin_amdgcn_mfma_f32_16x16x32_bf16(af, bf3, acc3, 0, 0, 0);
        }
        __syncthreads();
    }

    const int orow = row0 + wave * 16 + (lane >> 4) * 4;
    f32x4 accs[4] = {acc0, acc1, acc2, acc3};

    if (MODE == 3) {
        // interleaved mu/ls -> z, z_, kl.  accs[n0] = mu half, accs[n0+2] = ls half.
        float kls = 0.f;
#pragma unroll
        for (int n0 = 0; n0 < 2; ++n0) {
            int zc = bx * 32 + n0 * 16 + frow;
            float bmu = bias[zc];
            float bls = bias2[zc];
#pragma unroll
            for (int j = 0; j < 4; ++j) {
                int row = orow + j;
                float m = accs[n0][j]     + bmu;
                float l = accs[n0 + 2][j] + bls;
                float s = expf(l);
                size_t ei = (size_t)row * 512 + zc;
                z0[(size_t)row * 832 + zc] = f2bf(m + aux0[ei] * s);
                z1[ei]                     = f2bf(m + aux1[ei] * s);
                kls += -0.5f * (1.f + 2.f * l - m * m - expf(2.f * l));
            }
        }
#pragma unroll
        for (int off = 32; off >= 1; off >>= 1) kls += __shfl_xor(kls, off);
        __shared__ float redS[4];
        if (lane == 0) redS[wave] = kls;
        __syncthreads();
        if (threadIdx.x == 0) atomicAdd(accv, redS[0] + redS[1] + redS[2] + redS[3]);
        return;
    }

    float fsum = 0.f;
#pragma unroll
    for (int n0 = 0; n0 < 4; ++n0) {
        int col = col0 + n0 * 16 + frow;
        float bs = bias[col < Nreal ? col : Nreal - 1];
#pragma unroll
        for (int j = 0; j < 4; ++j) {
            float v = accs[n0][j] + bs;
            if (ACT == 1)      v = v > 0.f ? v : 0.f;
            else if (ACT == 2) v = v > 0.f ? v : 0.2f * v;
            else if (ACT == 3) v = 1.f / (1.f + expf(-v));
            if (MODE == 2) {
                if (col < Nreal) {
                    float d = v - aux0[(size_t)(orow + j) * 300 + col];
                    fsum += d * d;
                }
            } else {
                size_t idx = (size_t)(orow + j) * ldc + col;
                if (MODE == 1) ((float*)Cv)[idx] = v;
                else           ((short*)Cv)[idx] = f2bf(v);
            }
        }
    }
    if (MODE == 2) {
#pragma unroll
        for (int off = 32; off >= 1; off >>= 1) fsum += __shfl_xor(fsum, off);
        __shared__ float redF[4];
        if (lane == 0) redF[wave] = fsum;
        __syncthreads();
        if (threadIdx.x == 0) atomicAdd(accv, redF[0] + redF[1] + redF[2] + redF[3]);
    }
}

// ================= stages 1-4 =================
__global__ __launch_bounds__(256) void stage1(const short* Rb, const short* w_qi1t, const float* qi1_b, short* Ehb,
                                              const short* xcat, const short* w_fc1t, const float* fc1_b, short* h1)
{
    __shared__ short As[64][72];
    __shared__ short Bs[64][72];
    int b = blockIdx.x;
    if (b < 64)
        gemm_core<2,0>(As, Bs, b & 7, b >> 3, Rb, w_qi1t, qi1_b, nullptr, Ehb, 512, 320, 512,
                       nullptr, nullptr, nullptr, nullptr, nullptr);
    else {
        b -= 64;
        gemm_core<1,0>(As, Bs, b % 5, b / 5, xcat, w_fc1t, fc1_b, nullptr, h1, 300, 640, 320,
                       nullptr, nullptr, nullptr, nullptr, nullptr);
    }
}

__global__ __launch_bounds__(256) void stage2(const short* Ehb, const short* w_qi2t, const float* qi2_b, float* E,
                                              const short* h1, const short* w_mulst,
                                              const float* mu_b, const float* ls_b,
                                              const float* eps1, const float* eps2,
                                              short* zcat, short* zb, float* acc)
{
    __shared__ short As[64][72];
    __shared__ short Bs[64][72];
    int b = blockIdx.x;
    if (b < 64)
        gemm_core<2,1>(As, Bs, b & 7, b >> 3, Ehb, w_qi2t, qi2_b, nullptr, E, 512, 512, 512,
                       nullptr, nullptr, nullptr, nullptr, nullptr);
    else {
        b -= 64;
        gemm_core<0,3>(As, Bs, b & 15, b >> 4, h1, w_mulst, mu_b, ls_b, nullptr, 1024, 320, 0,
                       eps1, eps2, zcat, zb, acc);
    }
}

__global__ __launch_bounds__(256) void stage3(const short* zcat, const short* w_fc3t, const float* fc3_b, short* h3,
                                              const short* zb, const short* w_qz1t, const float* qz1_b, short* t1)
{
    __shared__ short As[64][72];
    __shared__ short Bs[64][72];
    int b = blockIdx.x;
    if (b < 160)
        gemm_core<1,0>(As, Bs, b % 5, b / 5, zcat, w_fc3t, fc3_b, nullptr, h3, 300, 832, 320,
                       nullptr, nullptr, nullptr, nullptr, nullptr);
    else {
        b -= 160;
        gemm_core<2,0>(As, Bs, b & 7, b >> 3, zb, w_qz1t, qz1_b, nullptr, t1, 512, 512, 512,
                       nullptr, nullptr, nullptr, nullptr, nullptr);
    }
}

__global__ __launch_bounds__(256) void stage4(const short* h3, const short* w_fc4t, const float* fc4_b,
                                              const float* xf, float* acc,
                                              const short* t1, const short* w_qz2t, const float* qz2_b, float* zp)
{
    __shared__ short As[64][72];
    __shared__ short Bs[64][72];
    int b = blockIdx.x;
    if (b < 160)
        gemm_core<3,2>(As, Bs, b % 5, b / 5, h3, w_fc4t, fc4_b, nullptr, nullptr, 300, 320, 0,
                       xf, nullptr, nullptr, nullptr, acc + 1);
    else {
        b -= 160;
        gemm_core<2,1>(As, Bs, b & 7, b >> 3, t1, w_qz2t, qz2_b, nullptr, zp, 512, 512, 512,
                       nullptr, nullptr, nullptr, nullptr, nullptr);
    }
}

// ================= STAGE 5: contrastive loss + finalize =================
__global__ __launch_bounds__(256) void stage5(const float* __restrict__ zp,
                                              const float* __restrict__ E,
                                              const int* __restrict__ top_idx,
                                              const int* __restrict__ dis_idx,
                                              float* __restrict__ acc,
                                              float* __restrict__ out)
{
    int lane = threadIdx.x & 63;
    int wave = threadIdx.x >> 6;
    int r    = blockIdx.x * 4 + wave;
    const float* z = zp + (size_t)r * LAT;
    const float4 za = reinterpret_cast<const float4*>(z)[lane * 2 + 0];
    const float4 zb = reinterpret_cast<const float4*>(z)[lane * 2 + 1];

    int ids[21];
    ids[0] = top_idx[r];
#pragma unroll
    for (int n = 0; n < 20; ++n) ids[n + 1] = dis_idx[r * 20 + n];

    float lg[21];
#pragma unroll
    for (int t = 0; t < 21; ++t) {
        const float* e = E + (size_t)ids[t] * LAT;
        const float4 ea = reinterpret_cast<const float4*>(e)[lane * 2 + 0];
        const float4 eb = reinterpret_cast<const float4*>(e)[lane * 2 + 1];
        float d = za.x * ea.x + za.y * ea.y + za.z * ea.z + za.w * ea.w
                + zb.x * eb.x + zb.y * eb.y + zb.z * eb.z + zb.w * eb.w;
#pragma unroll
        for (int off = 32; off >= 1; off >>= 1) d += __shfl_xor(d, off);
        lg[t] = d / 0.07f;
    }
    float m = lg[0];
#pragma unroll
    for (int t = 1; t < 21; ++t) m = fmaxf(m, lg[t]);
    float s = 0.f;
#pragma unroll
    for (int t = 0; t < 21; ++t) s += expf(lg[t] - m);
    float loss = logf(s) + m - lg[0];

    __shared__ float red[4];
    if (lane == 0) red[wave] = loss;
    __syncthreads();
    if (threadIdx.x == 0) {
        atomicAdd(&acc[2], red[0] + red[1] + red[2] + red[3]);
        __threadfence();
        unsigned old = atomicAdd((unsigned*)acc + 3, 1u);
        if (old == (unsigned)(gridDim.x - 1)) {
            __threadfence();
            volatile float* va = acc;
            out[0] = va[0] + va[1];   // kl + recon
            out[1] = va[2];           // csl
        }
    }
}

// ================= launcher =================
extern "C" void kernel_launch(void* const* d_in, const int* in_sizes, int n_in,
                              void* d_out, int out_size, void* d_ws, size_t ws_size,
                              hipStream_t stream)
{
    const float* logits   = (const float*)d_in[0];
    const int*   rels     = (const int*)  d_in[1];
    const float* rel_dict = (const float*)d_in[2];
    const float* fc1_w    = (const float*)d_in[3];
    const float* fc1_b    = (const float*)d_in[4];
    const float* fc2mu_w  = (const float*)d_in[5];
    const float* fc2mu_b  = (const float*)d_in[6];
    const float* fc2ls_w  = (const float*)d_in[7];
    const float* fc2ls_b  = (const float*)d_in[8];
    const float* fc3_w    = (const float*)d_in[9];
    const float* fc3_b    = (const float*)d_in[10];
    const float* fc4_w    = (const float*)d_in[11];
    const float* fc4_b    = (const float*)d_in[12];
    const float* qi1_w    = (const float*)d_in[13];
    const float* qi1_b    = (const float*)d_in[14];
    const float* qi2_w    = (const float*)d_in[15];
    const float* qi2_b    = (const float*)d_in[16];
    const float* qz1_w    = (const float*)d_in[17];
    const float* qz1_b    = (const float*)d_in[18];
    const float* qz2_w    = (const float*)d_in[19];
    const float* qz2_b    = (const float*)d_in[20];
    const float* eps1     = (const float*)d_in[21];
    const float* eps2     = (const float*)d_in[22];
    float* out = (float*)d_out;

    char* wsb = (char*)d_ws;
    size_t off = 0;
    auto alloc = [&](size_t bytes) -> void* {
        off = (off + 255) & ~(size_t)255;
        void* p = wsb + off;
        off += bytes;
        return p;
    };
    float* acc     = (float*)alloc(16);                       // kl, recon, csl, cnt
    int*   top_idx = (int*)  alloc((size_t)B * 4);
    int*   dis_idx = (int*)  alloc((size_t)B * 20 * 4);
    short* Rb      = (short*)alloc((size_t)NRELS * 320 * 2);
    short* Ehb     = (short*)alloc((size_t)NRELS * 512 * 2);
    float* E       = (float*)alloc((size_t)NRELS * 512 * 4);
    short* xcat    = (short*)alloc((size_t)B * 640 * 2);
    float* xf      = (float*)alloc((size_t)B * 300 * 4);
    short* h1      = (short*)alloc((size_t)B * 320 * 2);
    short* zcat    = (short*)alloc((size_t)B * 832 * 2);
    short* zb      = (short*)alloc((size_t)B * 512 * 2);
    short* h3      = (short*)alloc((size_t)B * 320 * 2);
    short* t1      = (short*)alloc((size_t)B * 512 * 2);

    short* w_qi1t  = (short*)alloc((size_t)512 * 320 * 2);
    short* w_qi2t  = (short*)alloc((size_t)512 * 512 * 2);
    short* w_fc1t  = (short*)alloc((size_t)320 * 640 * 2);
    short* w_mulst = (short*)alloc((size_t)1024 * 320 * 2);  // interleaved mu/ls
    short* w_fc3t  = (short*)alloc((size_t)320 * 832 * 2);
    short* w_fc4t  = (short*)alloc((size_t)320 * 320 * 2);
    short* w_qz1t  = (short*)alloc((size_t)512 * 512 * 2);
    short* w_qz2t  = (short*)alloc((size_t)512 * 512 * 2);

    // transpose-tile table: tiles = tk * ceil(N/64); tk = Kpad/64
    WPack p;
    //         src      dst      K    N   Kpad  Npad ilv off tstart tk
    p.d[0] = {qi1_w,   w_qi1t,  300, 512, 320,  512, 0, 0,    0,  5};   // 40
    p.d[1] = {qi2_w,   w_qi2t,  512, 512, 512,  512, 0, 0,   40,  8};   // 64
    p.d[2] = {fc1_w,   w_fc1t,  600, 300, 640,  320, 0, 0,  104, 10};   // 50
    p.d[3] = {fc2mu_w, w_mulst, 300, 512, 320, 1024, 1, 0,  154,  5};   // 40
    p.d[4] = {fc2ls_w, w_mulst, 300, 512, 320, 1024, 1, 32, 194,  5};   // 40
    p.d[5] = {fc3_w,   w_fc3t,  812, 300, 832,  320, 0, 0,  234, 13};   // 65
    p.d[6] = {fc4_w,   w_fc4t,  300, 300, 320,  320, 0, 0,  299,  5};   // 25
    p.d[7] = {qz1_w,   w_qz1t,  512, 512, 512,  512, 0, 0,  324,  8};   // 64
    p.d[8] = {qz2_w,   w_qz2t,  512, 512, 512,  512, 0, 0,  388,  8};   // 64 -> 452

    float* zp = out + 2 + 512;   // z_rel rows 1..B

    stage0<<<1093, 256, 0, stream>>>(p, logits, rels, rel_dict, top_idx, dis_idx,
                                     xcat, xf, zcat, Rb, acc, out);
    stage1<<<224, 256, 0, stream>>>(Rb, w_qi1t, qi1_b, Ehb, xcat, w_fc1t, fc1_b, h1);
    stage2<<<576, 256, 0, stream>>>(Ehb, w_qi2t, qi2_b, E, h1, w_mulst, fc2mu_b, fc2ls_b,
                                    eps1, eps2, zcat, zb, acc);
    stage3<<<416, 256, 0, stream>>>(zcat, w_fc3t, fc3_b, h3, zb, w_qz1t, qz1_b, t1);
    stage4<<<416, 256, 0, stream>>>(h3, w_fc4t, fc4_b, xf, acc, t1, w_qz2t, qz2_b, zp);
    stage5<<<B / 4, 256, 0, stream>>>(zp, E, top_idx, dis_idx, acc, out);
}